// Round 8
// baseline (338.242 us; speedup 1.0000x reference)
//
#include <hip/hip_runtime.h>
#include <cstdint>
#include <cstddef>

// ============================================================================
// CellSetAttentionNetwork: X[8,2048,512] fp32, single-head attention D=H=512.
// Pipeline: cvt(all) -> QKV gemm2 -> scores gemm2 (exp + rowsum fused) ->
//           PV gemm2 (1/rowsum fused) -> fused out-proj+residual+LayerNorm.
// R14: replace the GEMM engine with the guide's VERIFIED minimum-2-phase
// recipe (m230/m248: 666-682 TF refcheck'd at 256^2,K=1024):
//   - 256x256 tile (PV 128x256), BK=64, 8 waves (wave tile 128x64/64x64),
//     TWO LDS buffers (128/96KB, 1 blk/CU by design - m201 runs 1 blk/CU at
//     62% MfmaUtil).
//   - loop: stage(t+1 -> cur^1) FIRST; compute(cur) [64 MFMA/wave = ~620cy
//     MFMA window per SIMD > L2 latency -> loads drain under compute];
//     lgkmcnt(0) [reads complete before buffer can be overwritten -
//     REQUIRED with 2 buffers: cross-wave in-flight-read hazard];
//     vmcnt(0); ONE barrier; cur^=1.
//   Root cause of the R6-R13 ~450TF ceiling: at BK=32 the per-SIMD MFMA
//   window (~155cy) < load latency (~300-600cy) -> every iter exposes
//   latency regardless of prefetch depth. BK=64 + 256-wide fixes the ratio.
//   - BK=64 rows are 128B -> 16-way ds_read conflict; R12's verified
//     both-sides chunk swizzle reused (measured 0 conflicts): LDS slot s of
//     row r holds logical chunk s^(r&7); gld16 writes linearly so lane l
//     fetches global chunk (l&7)^(l>>3); read un-permutes with (c)^(lr&7).
// MODE 4 (out-proj+bo+residual+LayerNorm, R13-proven) and cvt kept as-is.
// Softmax max-free: scores stores E=exp(s*scale)+rowsum atomics; PV divides.
//
// ws layout (byte offsets):
//   [0, 64M)      S/E [8][2048][2048] bf16
//   [0, 16M)      Xb  [16384][512] bf16 (overlay: dead before S written)
//   [64M, +2M)    Wt  [2048][512] bf16 (Wq^T,Wk^T,Wv^T,Wo^T stacked)
//   [66M, +16M)   q   [16384][512] bf16; reused as ctx after scores gemm
//   [82M, +16M)   k   [16384][512] bf16
//   [98M, +16M)   vT  [8][512][2048] bf16
//   [114M, +64K)  rowsum fp32[16384]
// ============================================================================

typedef __bf16 bf16x8 __attribute__((ext_vector_type(8)));
typedef float  f32x4  __attribute__((ext_vector_type(4)));

__device__ __forceinline__ uint16_t f2bf(float f) {
  union { float f; uint32_t u; } v; v.f = f;
  uint32_t r = v.u + 0x7FFFu + ((v.u >> 16) & 1u);   // RNE
  return (uint16_t)(r >> 16);
}

__device__ __forceinline__ void gld16(const uint16_t* g, uint16_t* l) {
  // async global->LDS, 16B per lane; LDS dest = wave-uniform base + lane*16
  __builtin_amdgcn_global_load_lds(
      (__attribute__((address_space(1))) void*)(g),
      (__attribute__((address_space(3))) void*)(l), 16, 0, 0);
}

// ============================================================================
// gemm2_k: minimum-2-phase engine. BK=64, 8 waves in 2x4 grid, wave tile
// (BM/2)x64. BM in {128,256}, BN=256. K % 64 == 0, K/64 >= 2.
// MODE 0: QKV   (out q, k normal [M][512]; v transposed vT[b][h][t], +bias)
// MODE 1: scores (out bf16 E=exp(s*scale), rowsum atomics), batch = z
// MODE 2: ctx = (E @ vT^T)/rowsum  (out bf16 [b*2048+n][512]), batch = z
// ============================================================================
template <int MODE, int BM, int BN>
__global__ __launch_bounds__(512, 2) void gemm2_k(
    const uint16_t* __restrict__ A, const uint16_t* __restrict__ Bt,
    void* __restrict__ OutA, uint16_t* __restrict__ OutK,
    uint16_t* __restrict__ OutVT, float* __restrict__ rsum, int K, int lda,
    int ldb, const float* __restrict__ b0, const float* __restrict__ b1,
    const float* __restrict__ b2, float scale) {
  constexpr int MT = (BM / 2) / 16;    // 8 (BM=256) or 4 (BM=128)
  constexpr int NT = (BN / 4) / 16;    // 4
  constexpr int AI = BM / 64;          // A gld16 issues per wave per K-tile
  constexpr int BI = BN / 64;          // B gld16 issues per wave per K-tile
  static_assert(NT == 4, "BN must be 256");
  __shared__ alignas(16) uint16_t As[2][BM * 64];
  __shared__ alignas(16) uint16_t Bs[2][BN * 64];

  const int tid = threadIdx.x;
  const int w = tid >> 6, lane = tid & 63;
  const int wm = w >> 2, wn = w & 3;   // 2x4 wave grid

  // bijective XCD chunk swizzle (m204); all grids have nwg % 8 == 0.
  const int gx = gridDim.x, gy = gridDim.y;
  const int nwg = gx * gy * gridDim.z;
  const int hw = blockIdx.x + gx * (blockIdx.y + gy * blockIdx.z);
  const int lg = (hw & 7) * (nwg >> 3) + (hw >> 3);
  const int bx = lg % gx, byz = lg / gx;
  const int by = byz % gy, z = byz / gy;

  const int m0 = by * BM, n0 = bx * BN;

  const uint16_t* Ab = A;
  const uint16_t* Bb = Bt;
  if (MODE == 1) { Ab += (size_t)z * 2048 * 512;  Bb += (size_t)z * 2048 * 512; }
  if (MODE == 2) { Ab += (size_t)z * 2048 * 2048; Bb += (size_t)z * 512 * 2048; }

  // staging: one gld16 per wave covers 8 rows x 64 k (1024B linear in LDS).
  // Chunk swizzle: LDS slot s of row r holds logical chunk s^(r&7); lane l
  // (dest row l>>3, slot l&7) fetches global chunk (l&7)^(l>>3).
  const int l3 = lane >> 3, l7 = lane & 7;
  const int csw = (l7 ^ l3) * 8;
  const uint16_t* gA = Ab + (size_t)(m0 + w * (BM / 8) + l3) * lda + csw;
  const uint16_t* gB = Bb + (size_t)(n0 + w * (BN / 8) + l3) * ldb + csw;

  auto stage = [&](int t, int b) {
    const int k0 = t * 64;
#pragma unroll
    for (int j = 0; j < AI; j++)
      gld16(gA + k0 + (size_t)(j * 8) * lda,
            &As[b][(w * (BM / 8) + j * 8) * 64]);
#pragma unroll
    for (int j = 0; j < BI; j++)
      gld16(gB + k0 + (size_t)(j * 8) * ldb,
            &Bs[b][(w * (BN / 8) + j * 8) * 64]);
  };

  f32x4 acc[MT][NT];
#pragma unroll
  for (int i = 0; i < MT; i++)
#pragma unroll
    for (int j = 0; j < NT; j++) acc[i][j] = (f32x4){0.f, 0.f, 0.f, 0.f};

  const int lr = lane & 15, q4 = lane >> 4;
  // fragment read: logical chunk (ks*4+q4) of row r lives in slot
  // (ks*4+q4)^(r&7); row bases are multiples of 8 so r&7 == lr&7.
  const int rc0 = ((q4) ^ (lr & 7)) * 8;
  const int rc1 = ((4 + q4) ^ (lr & 7)) * 8;

  const int NK = K >> 6;

  // ---- prologue ----
  stage(0, 0);
  asm volatile("s_waitcnt vmcnt(0)" ::: "memory");
  __builtin_amdgcn_s_barrier();

  // ---- main loop: ONE barrier per K-tile; next tile's loads issued at the
  // top, drained at the bottom (hidden under ~620cy of MFMA) ----
  int cur = 0;
  for (int t = 0; t < NK; ++t) {
    if (t + 1 < NK) stage(t + 1, cur ^ 1);
#pragma unroll
    for (int ks = 0; ks < 2; ks++) {
      const int rc = ks ? rc1 : rc0;
      bf16x8 af[MT], bfr[NT];
#pragma unroll
      for (int mt = 0; mt < MT; mt++)
        af[mt] = *(const bf16x8*)
            &As[cur][(wm * (BM / 2) + mt * 16 + lr) * 64 + rc];
#pragma unroll
      for (int nt = 0; nt < NT; nt++)
        bfr[nt] = *(const bf16x8*)&Bs[cur][(wn * 64 + nt * 16 + lr) * 64 + rc];
#pragma unroll
      for (int nt = 0; nt < NT; nt++)
#pragma unroll
        for (int mt = 0; mt < MT; mt++)
          acc[mt][nt] = __builtin_amdgcn_mfma_f32_16x16x32_bf16(
              af[mt], bfr[nt], acc[mt][nt], 0, 0, 0);
    }
    if (t + 1 < NK) {
      // all LDS reads complete before any wave may overwrite this buffer
      asm volatile("s_waitcnt lgkmcnt(0)" ::: "memory");
      asm volatile("s_waitcnt vmcnt(0)" ::: "memory");   // tile t+1 landed
      __builtin_amdgcn_s_barrier();
      cur ^= 1;
    }
  }

  // epilogue: C/D layout col=lane&15, row=quad*4+reg  (m89/m91 verified)
  if (MODE == 1) {
    uint16_t* Sp = (uint16_t*)OutA + (size_t)z * 2048 * 2048;
#pragma unroll
    for (int mt = 0; mt < MT; mt++) {
      float rp[4] = {0.f, 0.f, 0.f, 0.f};
#pragma unroll
      for (int nt = 0; nt < NT; nt++) {
#pragma unroll
        for (int i = 0; i < 4; i++) {
          const int row = m0 + wm * (BM / 2) + mt * 16 + q4 * 4 + i;
          const int col = n0 + wn * 64 + nt * 16 + lr;
          const float e = __expf(acc[mt][nt][i] * scale);
          Sp[(size_t)row * 2048 + col] = f2bf(e);
          rp[i] += e;
        }
      }
#pragma unroll
      for (int i = 0; i < 4; i++) {
        float p = rp[i];
        p += __shfl_xor(p, 1); p += __shfl_xor(p, 2);
        p += __shfl_xor(p, 4); p += __shfl_xor(p, 8);
        if (lr == 0) {
          const int row = m0 + wm * (BM / 2) + mt * 16 + q4 * 4 + i;
          atomicAdd(&rsum[z * 2048 + row], p);
        }
      }
    }
  } else if (MODE == 2) {
#pragma unroll
    for (int mt = 0; mt < MT; mt++) {
#pragma unroll
      for (int i = 0; i < 4; i++) {
        const int row = m0 + wm * (BM / 2) + mt * 16 + q4 * 4 + i;
        const float sc = 1.0f / rsum[z * 2048 + row];
#pragma unroll
        for (int nt = 0; nt < NT; nt++) {
          const int col = n0 + wn * 64 + nt * 16 + lr;
          ((uint16_t*)OutA)[((size_t)z * 2048 + row) * 512 + col] =
              f2bf(acc[mt][nt][i] * sc);
        }
      }
    }
  } else {  // MODE 0
#pragma unroll
    for (int mt = 0; mt < MT; mt++) {
#pragma unroll
      for (int nt = 0; nt < NT; nt++) {
#pragma unroll
        for (int i = 0; i < 4; i++) {
          const int row = m0 + wm * (BM / 2) + mt * 16 + q4 * 4 + i;
          const int col = n0 + wn * 64 + nt * 16 + lr;
          const float v = acc[mt][nt][i];
          const int which = col >> 9, c = col & 511;
          if (which == 0) {
            ((uint16_t*)OutA)[(size_t)row * 512 + c] = f2bf(v + b0[c]);
          } else if (which == 1) {
            OutK[(size_t)row * 512 + c] = f2bf(v + b1[c]);
          } else {  // v -> transposed vT[b][h][t]
            OutVT[(size_t)(row >> 11) * (512 * 2048) + (size_t)c * 2048 +
                  (row & 2047)] = f2bf(v + b2[c]);
          }
        }
      }
    }
  }
}

// ============================================================================
// gemm_k MODE 4 (R13-proven): out-proj + b0 + Xres residual + LayerNorm,
// BM=64 x BN=512 (block owns full rows). R7/R10 3-buffer BK=32 K-loop.
// ============================================================================
template <int MODE, int BM, int BN, int WM, int WN>
__global__ __launch_bounds__(512, 4) void gemm_k(
    const uint16_t* __restrict__ A, const uint16_t* __restrict__ Bt,
    void* __restrict__ OutA, float* __restrict__ rsum, int K, int lda,
    int ldb, const float* __restrict__ b0, const float* __restrict__ b1,
    const float* __restrict__ b2, const float* __restrict__ Xres) {
  constexpr int MT = (BM / WM) / 16;
  constexpr int NT = (BN / WN) / 16;
  static_assert(MT == 4 && NT == 4, "wave tile must be 64x64");
  constexpr int AI = (BM >= 128) ? BM / 128 : 1;
  constexpr int BI = BN / 128;
  constexpr int PW = AI + BI;
  __shared__ alignas(16) uint16_t As[3][BM * 32];
  __shared__ alignas(16) uint16_t Bs[3][BN * 32];

  const int tid = threadIdx.x;
  const int w = tid >> 6, lane = tid & 63;
  const int wm = w / WN, wn = w % WN;

  const int gx = gridDim.x, gy = gridDim.y;
  const int nwg = gx * gy * gridDim.z;
  const int hw = blockIdx.x + gx * (blockIdx.y + gy * blockIdx.z);
  const int lg = (hw & 7) * (nwg >> 3) + (hw >> 3);
  const int bx = lg % gx, byz = lg / gx;
  const int by = byz % gy;

  const int m0 = by * BM, n0 = bx * BN;

  const uint16_t* Ab = A;
  const uint16_t* Bb = Bt;

  const int kc = (((lane & 3) ^ ((lane >> 2) & 3) ^ (lane >> 4)) * 8);
  const int rbA = (BM >= 128) ? w * (BM / 8) : (w & 3) * 16;
  const int rbB = w * (BN / 8);
  const uint16_t* gA = Ab + (size_t)(m0 + rbA + (lane >> 2)) * lda + kc;
  const uint16_t* gB = Bb + (size_t)(n0 + rbB + (lane >> 2)) * ldb + kc;

  f32x4 acc[MT][NT];
#pragma unroll
  for (int i = 0; i < MT; i++)
#pragma unroll
    for (int j = 0; j < NT; j++) acc[i][j] = (f32x4){0.f, 0.f, 0.f, 0.f};

  const int lr = lane & 15, q4 = lane >> 4;
  const int swz = (((lane >> 4) ^ (lr & 3) ^ (lr >> 2)) * 8);
  const int iters = K >> 5;

  auto stage = [&](int t, int buf) {
    const int k0 = t * 32;
#pragma unroll
    for (int j = 0; j < AI; j++)
      gld16(gA + k0 + (size_t)(j * 16) * lda, &As[buf][(rbA + j * 16) * 32]);
#pragma unroll
    for (int j = 0; j < BI; j++)
      gld16(gB + k0 + (size_t)(j * 16) * ldb, &Bs[buf][(rbB + j * 16) * 32]);
  };

  auto compute = [&](int buf) {
    bf16x8 af[MT], bfr[NT];
#pragma unroll
    for (int t = 0; t < MT; t++)
      af[t] = *(const bf16x8*)&As[buf][(wm * (BM / WM) + t * 16 + lr) * 32 + swz];
#pragma unroll
    for (int t = 0; t < NT; t++)
      bfr[t] = *(const bf16x8*)&Bs[buf][(wn * (BN / WN) + t * 16 + lr) * 32 + swz];
#pragma unroll
    for (int nt = 0; nt < NT; nt++)
#pragma unroll
      for (int mt = 0; mt < MT; mt++)
        acc[mt][nt] = __builtin_amdgcn_mfma_f32_16x16x32_bf16(
            af[mt], bfr[nt], acc[mt][nt], 0, 0, 0);
  };

  stage(0, 0);
  stage(1, 1);
  int buf = 0;
  for (int i = 0; i < iters - 1; ++i) {
    asm volatile("s_waitcnt vmcnt(%0)" ::"i"(PW) : "memory");
    __builtin_amdgcn_s_barrier();
    if (i + 2 < iters) stage(i + 2, (buf + 2 >= 3) ? buf - 1 : buf + 2);
    compute(buf);
    buf = (buf == 2) ? 0 : buf + 1;
  }
  asm volatile("s_waitcnt vmcnt(0)" ::: "memory");
  __builtin_amdgcn_s_barrier();
  compute(buf);

  // fused: v = acc + bo + X; LayerNorm over the full 512-row; fp32 out.
  __shared__ float redS[8][64];
  __shared__ float redQ[8][64];
  float* Op = (float*)OutA;
  __syncthreads();   // all waves done reading As/Bs fragments
#pragma unroll
  for (int mt = 0; mt < MT; mt++) {
#pragma unroll
    for (int i = 0; i < 4; i++) {
      const int rl = mt * 16 + q4 * 4 + i;
      const int row = m0 + rl;
      float ps = 0.f, pq = 0.f;
#pragma unroll
      for (int nt = 0; nt < NT; nt++) {
        const int col = wn * 64 + nt * 16 + lr;
        float v = acc[mt][nt][i] + b0[col] + Xres[(size_t)row * 512 + col];
        acc[mt][nt][i] = v;
        ps += v; pq += v * v;
      }
      ps += __shfl_xor(ps, 1); pq += __shfl_xor(pq, 1);
      ps += __shfl_xor(ps, 2); pq += __shfl_xor(pq, 2);
      ps += __shfl_xor(ps, 4); pq += __shfl_xor(pq, 4);
      ps += __shfl_xor(ps, 8); pq += __shfl_xor(pq, 8);
      if (lr == 0) { redS[w][rl] = ps; redQ[w][rl] = pq; }
    }
  }
  __syncthreads();
#pragma unroll
  for (int mt = 0; mt < MT; mt++) {
#pragma unroll
    for (int i = 0; i < 4; i++) {
      const int rl = mt * 16 + q4 * 4 + i;
      const int row = m0 + rl;
      float s8 = 0.f, q8 = 0.f;
#pragma unroll
      for (int ww = 0; ww < 8; ww++) { s8 += redS[ww][rl]; q8 += redQ[ww][rl]; }
      const float mean = s8 * (1.f / 512.f);
      const float var = q8 * (1.f / 512.f) - mean * mean;
      const float rstd = rsqrtf(var + 1e-5f);
#pragma unroll
      for (int nt = 0; nt < NT; nt++) {
        const int col = wn * 64 + nt * 16 + lr;
        Op[(size_t)row * 512 + col] =
            (acc[mt][nt][i] - mean) * rstd * b1[col] + b2[col];
      }
    }
  }
}

// Fused conversions: X fp32->bf16 (8.39M elems, 4/thread), Wt transpose
// (first 1.05M threads), rowsum zeroing (first 16384 threads).
__global__ __launch_bounds__(256) void cvt_all_k(
    const float* __restrict__ X, uint16_t* __restrict__ Xb,
    const float* __restrict__ Wq, const float* __restrict__ Wk,
    const float* __restrict__ Wv, const float* __restrict__ Wo,
    uint16_t* __restrict__ Wt, float* __restrict__ rsum) {
  const int i = blockIdx.x * 256 + threadIdx.x;   // 0..2097151
  const float4 f = ((const float4*)X)[i];
  uint32_t lo = (uint32_t)f2bf(f.x) | ((uint32_t)f2bf(f.y) << 16);
  uint32_t hi = (uint32_t)f2bf(f.z) | ((uint32_t)f2bf(f.w) << 16);
  ((uint2*)Xb)[i] = make_uint2(lo, hi);
  if (i < 16384) rsum[i] = 0.f;
  if (i < 2048 * 512) {   // Wt[n][k] = W[k][n&511]
    const int n = i >> 9, kk = i & 511;
    const int which = n >> 9, c = n & 511;
    const float* W =
        (which == 0) ? Wq : (which == 1) ? Wk : (which == 2) ? Wv : Wo;
    Wt[i] = f2bf(W[kk * 512 + c]);
  }
}

extern "C" void kernel_launch(void* const* d_in, const int* in_sizes, int n_in,
                              void* d_out, int out_size, void* d_ws,
                              size_t ws_size, hipStream_t stream) {
  const float* X     = (const float*)d_in[0];
  const float* Wq    = (const float*)d_in[1];
  const float* bq    = (const float*)d_in[2];
  const float* Wk    = (const float*)d_in[3];
  const float* bk    = (const float*)d_in[4];
  const float* Wv    = (const float*)d_in[5];
  const float* bv    = (const float*)d_in[6];
  const float* Wo    = (const float*)d_in[7];
  const float* bo    = (const float*)d_in[8];
  const float* gamma = (const float*)d_in[9];
  const float* beta  = (const float*)d_in[10];
  float* out = (float*)d_out;

  char* ws = (char*)d_ws;   // ~114.1 MB used (overlaid layout, see header)
  uint16_t* S    = (uint16_t*)(ws);                 // [0, 64M)
  uint16_t* Xb   = (uint16_t*)(ws);                 // [0, 16M) overlay on S
  uint16_t* Wt   = (uint16_t*)(ws + 67108864);      // [64M, 66M)
  uint16_t* q    = (uint16_t*)(ws + 69206016);      // [66M, 82M), later ctx
  uint16_t* kb   = (uint16_t*)(ws + 85983232);      // [82M, 98M)
  uint16_t* vT   = (uint16_t*)(ws + 102760448);     // [98M, 114M) [8][512][2048]
  float*    rsum = (float*)(ws + 119537664);        // [114M, +64K) fp32[16384]
  uint16_t* ctx  = q;                               // overlay: q dead after scores

  cvt_all_k<<<dim3(8192), dim3(256), 0, stream>>>(X, Xb, Wq, Wk, Wv, Wo, Wt,
                                                  rsum);
  // QKV: M=16384, N=1536, K=512, tile 256x256 (384 blocks)
  gemm2_k<0, 256, 256><<<dim3(6, 64, 1), dim3(512), 0, stream>>>(
      Xb, Wt, (void*)q, kb, vT, nullptr, 512, 512, 512, bq, bk, bv, 1.f);
  // scores: per batch M=N=2048, K=512; tile 256x256 (512 blocks, 1 z/XCD)
  gemm2_k<1, 256, 256><<<dim3(8, 8, 8), dim3(512), 0, stream>>>(
      q, kb, (void*)S, nullptr, nullptr, rsum, 512, 512, 512, nullptr, nullptr,
      nullptr, 0.044194173824159216f);
  // ctx = (E @ V)/rowsum: per batch M=2048, N=512, K=2048, tile 128x256
  gemm2_k<2, 128, 256><<<dim3(2, 16, 8), dim3(512), 0, stream>>>(
      S, vT, (void*)ctx, nullptr, nullptr, rsum, 2048, 2048, 2048, nullptr,
      nullptr, nullptr, 1.f);
  // fused out-proj + bo + X residual + LayerNorm: M=16384, N=512, K=512,
  // tile 64x512 (256 blocks, each owns full rows)
  gemm_k<4, 64, 512, 1, 8><<<dim3(1, 256, 1), dim3(512), 0, stream>>>(
      ctx, Wt + 1536 * 512, (void*)out, nullptr, 512, 512, 512, bo, gamma,
      beta, X);
}

// Round 9
// 320.115 us; speedup vs baseline: 1.0566x; 1.0566x over previous
//
#include <hip/hip_runtime.h>
#include <cstdint>
#include <cstddef>

// ============================================================================
// CellSetAttentionNetwork: X[8,2048,512] fp32, single-head attention D=H=512.
// Pipeline: cvt(all) -> QKV gemm -> scores gemm (exp + rowsum fused) ->
//           PV gemm (1/rowsum fused) -> fused out-proj+residual+LayerNorm.
// R15: compose the two proven-best components; no new structure.
//  - gemm_k = R6/R7 engine VERBATIM (256 thr, 4 waves 2x2, 128^2 / 64x128
//    tiles, 3 LDS buffers 48KB, depth-2 prefetch, ONE barrier/iter,
//    s_waitcnt vmcnt(PW) never 0 mid-loop): each dispatch proven ~75.5us
//    (R6/R7 totals 328 = cvt+4x75.5+ln). Every structural "improvement"
//    since (R8 2-buf, R12 phase-split, R14 gemm2 256^2) was <= neutral.
//  - + bijective XCD chunk swizzle (m204; proven FETCH 68.7->21.7MB, never
//    negative).
//  - gemmf_k = R13 MODE-4 fused out-proj+bo+residual+LayerNorm VERBATIM
//    (512 thr, 64x512, block owns full rows; proven ~35-45us, replaces
//    out-gemm 75.5 + ln_k 12).
// Session lesson (R10 84us vs R13 101us, same binary): per-dispatch time is
// +-20% noisy; judge by totals only.
// Softmax max-free: scores stores E=exp(s*scale)+rowsum atomics; PV divides.
//
// ws layout (byte offsets):
//   [0, 64M)      S/E [8][2048][2048] bf16
//   [0, 16M)      Xb  [16384][512] bf16 (overlay: dead before S written)
//   [64M, +2M)    Wt  [2048][512] bf16 (Wq^T,Wk^T,Wv^T,Wo^T stacked)
//   [66M, +16M)   q   [16384][512] bf16; reused as ctx after scores gemm
//   [82M, +16M)   k   [16384][512] bf16
//   [98M, +16M)   vT  [8][512][2048] bf16
//   [114M, +64K)  rowsum fp32[16384]
// ============================================================================

typedef __bf16 bf16x8 __attribute__((ext_vector_type(8)));
typedef float  f32x4  __attribute__((ext_vector_type(4)));

__device__ __forceinline__ uint16_t f2bf(float f) {
  union { float f; uint32_t u; } v; v.f = f;
  uint32_t r = v.u + 0x7FFFu + ((v.u >> 16) & 1u);   // RNE
  return (uint16_t)(r >> 16);
}

__device__ __forceinline__ void gld16(const uint16_t* g, uint16_t* l) {
  // async global->LDS, 16B per lane; LDS dest = wave-uniform base + lane*16
  __builtin_amdgcn_global_load_lds(
      (__attribute__((address_space(1))) void*)(g),
      (__attribute__((address_space(3))) void*)(l), 16, 0, 0);
}

// ============================================================================
// R6/R7 engine. 256 threads, 4 waves 2x2, wave tile (BM/2)x(BN/2), BK=32,
// 3 LDS buffers, depth-2 prefetch, one barrier/iter. K%32==0, K/32>=2.
// MODE 0: QKV   (out q, k normal [M][512]; v transposed vT[b][h][t], +bias)
// MODE 1: scores (out bf16 E=exp(s*scale), rowsum atomics), batch = z
// MODE 2: ctx = (E @ vT^T)/rowsum  (out bf16 [b*2048+n][512]), batch = z
// ============================================================================
template <int MODE, int BM, int BN>
__global__ __launch_bounds__(256, 2) void gemm_k(
    const uint16_t* __restrict__ A, const uint16_t* __restrict__ Bt,
    void* __restrict__ OutA, uint16_t* __restrict__ OutK,
    uint16_t* __restrict__ OutVT, float* __restrict__ rsum, int K, int lda,
    int ldb, const float* __restrict__ b0, const float* __restrict__ b1,
    const float* __restrict__ b2, float scale) {
  constexpr int MT = BM / 32;      // acc tiles per wave, m dim
  constexpr int NT = BN / 32;      // acc tiles per wave, n dim
  constexpr int AI = BM / 64;      // A gld16 issues per wave per k-tile
  constexpr int BI = BN / 64;      // B gld16 issues per wave per k-tile
  constexpr int PW = AI + BI;      // this wave's loads per k-tile (vmcnt unit)
  __shared__ alignas(16) uint16_t As[3][BM * 32];
  __shared__ alignas(16) uint16_t Bs[3][BN * 32];

  const int tid = threadIdx.x;
  const int w = tid >> 6, lane = tid & 63;
  const int wm = w >> 1, wn = w & 1;        // 2x2 wave grid

  // bijective XCD chunk swizzle (m204); all grids have nwg % 8 == 0.
  const int gx = gridDim.x, gy = gridDim.y;
  const int nwg = gx * gy * gridDim.z;
  const int hw = blockIdx.x + gx * (blockIdx.y + gy * blockIdx.z);
  const int lg = (hw & 7) * (nwg >> 3) + (hw >> 3);
  const int bx = lg % gx, byz = lg / gx;
  const int by = byz % gy, z = byz / gy;

  const int m0 = by * BM, n0 = bx * BN;

  const uint16_t* Ab = A;
  const uint16_t* Bb = Bt;
  if (MODE == 1) { Ab += (size_t)z * 2048 * 512;  Bb += (size_t)z * 2048 * 512; }
  if (MODE == 2) { Ab += (size_t)z * 2048 * 2048; Bb += (size_t)z * 512 * 2048; }

  // staging: one gld16 by a full wave covers 16 rows x 32 k (1024B linear).
  // k-chunk XOR swizzle (R7): neutral, reads un-permute with swz.
  const int kc = (((lane & 3) ^ ((lane >> 2) & 3) ^ (lane >> 4)) * 8);
  const int rbA = w * (BM / 4);             // this wave's A row base
  const int rbB = w * (BN / 4);             // this wave's B row base
  const uint16_t* gA = Ab + (size_t)(m0 + rbA + (lane >> 2)) * lda + kc;
  const uint16_t* gB = Bb + (size_t)(n0 + rbB + (lane >> 2)) * ldb + kc;

  f32x4 acc[MT][NT];
#pragma unroll
  for (int i = 0; i < MT; i++)
#pragma unroll
    for (int j = 0; j < NT; j++) acc[i][j] = (f32x4){0.f, 0.f, 0.f, 0.f};

  const int lr = lane & 15, q4 = lane >> 4;
  const int swz = (((lane >> 4) ^ (lr & 3) ^ (lr >> 2)) * 8);
  const int iters = K >> 5;

  auto stage = [&](int t, int buf) {
    const int k0 = t * 32;
#pragma unroll
    for (int j = 0; j < AI; j++)
      gld16(gA + k0 + (size_t)(j * 16) * lda, &As[buf][(rbA + j * 16) * 32]);
#pragma unroll
    for (int j = 0; j < BI; j++)
      gld16(gB + k0 + (size_t)(j * 16) * ldb, &Bs[buf][(rbB + j * 16) * 32]);
  };

  auto compute = [&](int buf) {
    bf16x8 af[MT], bfr[NT];
#pragma unroll
    for (int t = 0; t < MT; t++)
      af[t] = *(const bf16x8*)&As[buf][(wm * (BM / 2) + t * 16 + lr) * 32 + swz];
#pragma unroll
    for (int t = 0; t < NT; t++)
      bfr[t] = *(const bf16x8*)&Bs[buf][(wn * (BN / 2) + t * 16 + lr) * 32 + swz];
#pragma unroll
    for (int nt = 0; nt < NT; nt++)
#pragma unroll
      for (int mt = 0; mt < MT; mt++)
        acc[mt][nt] = __builtin_amdgcn_mfma_f32_16x16x32_bf16(
            af[mt], bfr[nt], acc[mt][nt], 0, 0, 0);
  };

  // ---- depth-2 pipelined K-loop (R6/R7-proven): 1 barrier/iter, next
  // tile's loads stay in flight across it; vmcnt never 0 mid-loop ----
  stage(0, 0);
  stage(1, 1);
  int buf = 0;
  for (int i = 0; i < iters - 1; ++i) {
    asm volatile("s_waitcnt vmcnt(%0)" ::"i"(PW) : "memory");
    __builtin_amdgcn_s_barrier();   // tile i visible; buf of tile i-1 free
    if (i + 2 < iters) stage(i + 2, (buf + 2 >= 3) ? buf - 1 : buf + 2);
    compute(buf);
    buf = (buf == 2) ? 0 : buf + 1;
  }
  asm volatile("s_waitcnt vmcnt(0)" ::: "memory");
  __builtin_amdgcn_s_barrier();
  compute(buf);

  // epilogue: C/D layout col=lane&15, row=quad*4+reg  (m89/m91 verified)
  if (MODE == 1) {
    uint16_t* Sp = (uint16_t*)OutA + (size_t)z * 2048 * 2048;
#pragma unroll
    for (int mt = 0; mt < MT; mt++) {
      float rp[4] = {0.f, 0.f, 0.f, 0.f};
#pragma unroll
      for (int nt = 0; nt < NT; nt++) {
#pragma unroll
        for (int i = 0; i < 4; i++) {
          const int row = m0 + wm * (BM / 2) + mt * 16 + q4 * 4 + i;
          const int col = n0 + wn * (BN / 2) + nt * 16 + lr;
          const float e = __expf(acc[mt][nt][i] * scale);
          Sp[(size_t)row * 2048 + col] = f2bf(e);
          rp[i] += e;
        }
      }
#pragma unroll
      for (int i = 0; i < 4; i++) {
        float p = rp[i];
        p += __shfl_xor(p, 1); p += __shfl_xor(p, 2);
        p += __shfl_xor(p, 4); p += __shfl_xor(p, 8);
        if (lr == 0) {
          const int row = m0 + wm * (BM / 2) + mt * 16 + q4 * 4 + i;
          atomicAdd(&rsum[z * 2048 + row], p);
        }
      }
    }
  } else if (MODE == 2) {
#pragma unroll
    for (int mt = 0; mt < MT; mt++) {
#pragma unroll
      for (int i = 0; i < 4; i++) {
        const int row = m0 + wm * (BM / 2) + mt * 16 + q4 * 4 + i;
        const float sc = 1.0f / rsum[z * 2048 + row];
#pragma unroll
        for (int nt = 0; nt < NT; nt++) {
          const int col = n0 + wn * (BN / 2) + nt * 16 + lr;
          ((uint16_t*)OutA)[((size_t)z * 2048 + row) * 512 + col] =
              f2bf(acc[mt][nt][i] * sc);
        }
      }
    }
  } else {  // MODE 0
#pragma unroll
    for (int mt = 0; mt < MT; mt++) {
#pragma unroll
      for (int nt = 0; nt < NT; nt++) {
#pragma unroll
        for (int i = 0; i < 4; i++) {
          const int row = m0 + wm * (BM / 2) + mt * 16 + q4 * 4 + i;
          const int col = n0 + wn * (BN / 2) + nt * 16 + lr;
          const float v = acc[mt][nt][i];
          const int which = col >> 9, c = col & 511;
          if (which == 0) {
            ((uint16_t*)OutA)[(size_t)row * 512 + c] = f2bf(v + b0[c]);
          } else if (which == 1) {
            OutK[(size_t)row * 512 + c] = f2bf(v + b1[c]);
          } else {  // v -> transposed vT[b][h][t]
            OutVT[(size_t)(row >> 11) * (512 * 2048) + (size_t)c * 2048 +
                  (row & 2047)] = f2bf(v + b2[c]);
          }
        }
      }
    }
  }
}

// ============================================================================
// gemmf_k (R13-proven MODE 4): out-proj + b0 + Xres residual + LayerNorm,
// 512 threads, BM=64 x BN=512 (block owns full rows), 1x8 wave grid.
// R7/R10 3-buffer BK=32 K-loop; waves 4-7 redundantly re-stage A (same
// bytes+dest) so per-wave vmcnt(PW) stays uniform.
// ============================================================================
template <int BM, int BN, int WM, int WN>
__global__ __launch_bounds__(512, 4) void gemmf_k(
    const uint16_t* __restrict__ A, const uint16_t* __restrict__ Bt,
    void* __restrict__ OutA, int K, int lda, int ldb,
    const float* __restrict__ b0, const float* __restrict__ b1,
    const float* __restrict__ b2, const float* __restrict__ Xres) {
  constexpr int MT = (BM / WM) / 16;
  constexpr int NT = (BN / WN) / 16;
  static_assert(MT == 4 && NT == 4, "wave tile must be 64x64");
  constexpr int AI = (BM >= 128) ? BM / 128 : 1;
  constexpr int BI = BN / 128;
  constexpr int PW = AI + BI;
  __shared__ alignas(16) uint16_t As[3][BM * 32];
  __shared__ alignas(16) uint16_t Bs[3][BN * 32];

  const int tid = threadIdx.x;
  const int w = tid >> 6, lane = tid & 63;
  const int wm = w / WN, wn = w % WN;

  const int gx = gridDim.x, gy = gridDim.y;
  const int nwg = gx * gy * gridDim.z;
  const int hw = blockIdx.x + gx * (blockIdx.y + gy * blockIdx.z);
  const int lg = (hw & 7) * (nwg >> 3) + (hw >> 3);
  const int bx = lg % gx, byz = lg / gx;
  const int by = byz % gy;

  const int m0 = by * BM, n0 = bx * BN;

  const uint16_t* Ab = A;
  const uint16_t* Bb = Bt;

  const int kc = (((lane & 3) ^ ((lane >> 2) & 3) ^ (lane >> 4)) * 8);
  const int rbA = (BM >= 128) ? w * (BM / 8) : (w & 3) * 16;
  const int rbB = w * (BN / 8);
  const uint16_t* gA = Ab + (size_t)(m0 + rbA + (lane >> 2)) * lda + kc;
  const uint16_t* gB = Bb + (size_t)(n0 + rbB + (lane >> 2)) * ldb + kc;

  f32x4 acc[MT][NT];
#pragma unroll
  for (int i = 0; i < MT; i++)
#pragma unroll
    for (int j = 0; j < NT; j++) acc[i][j] = (f32x4){0.f, 0.f, 0.f, 0.f};

  const int lr = lane & 15, q4 = lane >> 4;
  const int swz = (((lane >> 4) ^ (lr & 3) ^ (lr >> 2)) * 8);
  const int iters = K >> 5;

  auto stage = [&](int t, int buf) {
    const int k0 = t * 32;
#pragma unroll
    for (int j = 0; j < AI; j++)
      gld16(gA + k0 + (size_t)(j * 16) * lda, &As[buf][(rbA + j * 16) * 32]);
#pragma unroll
    for (int j = 0; j < BI; j++)
      gld16(gB + k0 + (size_t)(j * 16) * ldb, &Bs[buf][(rbB + j * 16) * 32]);
  };

  auto compute = [&](int buf) {
    bf16x8 af[MT], bfr[NT];
#pragma unroll
    for (int t = 0; t < MT; t++)
      af[t] = *(const bf16x8*)&As[buf][(wm * (BM / WM) + t * 16 + lr) * 32 + swz];
#pragma unroll
    for (int t = 0; t < NT; t++)
      bfr[t] = *(const bf16x8*)&Bs[buf][(wn * (BN / WN) + t * 16 + lr) * 32 + swz];
#pragma unroll
    for (int nt = 0; nt < NT; nt++)
#pragma unroll
      for (int mt = 0; mt < MT; mt++)
        acc[mt][nt] = __builtin_amdgcn_mfma_f32_16x16x32_bf16(
            af[mt], bfr[nt], acc[mt][nt], 0, 0, 0);
  };

  stage(0, 0);
  stage(1, 1);
  int buf = 0;
  for (int i = 0; i < iters - 1; ++i) {
    asm volatile("s_waitcnt vmcnt(%0)" ::"i"(PW) : "memory");
    __builtin_amdgcn_s_barrier();
    if (i + 2 < iters) stage(i + 2, (buf + 2 >= 3) ? buf - 1 : buf + 2);
    compute(buf);
    buf = (buf == 2) ? 0 : buf + 1;
  }
  asm volatile("s_waitcnt vmcnt(0)" ::: "memory");
  __builtin_amdgcn_s_barrier();
  compute(buf);

  // fused: v = acc + bo + X; LayerNorm over the full 512-row; fp32 out.
  __shared__ float redS[8][64];
  __shared__ float redQ[8][64];
  float* Op = (float*)OutA;
  __syncthreads();   // all waves done reading As/Bs fragments
#pragma unroll
  for (int mt = 0; mt < MT; mt++) {
#pragma unroll
    for (int i = 0; i < 4; i++) {
      const int rl = mt * 16 + q4 * 4 + i;
      const int row = m0 + rl;
      float ps = 0.f, pq = 0.f;
#pragma unroll
      for (int nt = 0; nt < NT; nt++) {
        const int col = wn * 64 + nt * 16 + lr;
        float v = acc[mt][nt][i] + b0[col] + Xres[(size_t)row * 512 + col];
        acc[mt][nt][i] = v;
        ps += v; pq += v * v;
      }
      ps += __shfl_xor(ps, 1); pq += __shfl_xor(pq, 1);
      ps += __shfl_xor(ps, 2); pq += __shfl_xor(pq, 2);
      ps += __shfl_xor(ps, 4); pq += __shfl_xor(pq, 4);
      ps += __shfl_xor(ps, 8); pq += __shfl_xor(pq, 8);
      if (lr == 0) { redS[w][rl] = ps; redQ[w][rl] = pq; }
    }
  }
  __syncthreads();
#pragma unroll
  for (int mt = 0; mt < MT; mt++) {
#pragma unroll
    for (int i = 0; i < 4; i++) {
      const int rl = mt * 16 + q4 * 4 + i;
      const int row = m0 + rl;
      float s8 = 0.f, q8 = 0.f;
#pragma unroll
      for (int ww = 0; ww < 8; ww++) { s8 += redS[ww][rl]; q8 += redQ[ww][rl]; }
      const float mean = s8 * (1.f / 512.f);
      const float var = q8 * (1.f / 512.f) - mean * mean;
      const float rstd = rsqrtf(var + 1e-5f);
#pragma unroll
      for (int nt = 0; nt < NT; nt++) {
        const int col = wn * 64 + nt * 16 + lr;
        Op[(size_t)row * 512 + col] =
            (acc[mt][nt][i] - mean) * rstd * b1[col] + b2[col];
      }
    }
  }
}

// Fused conversions: X fp32->bf16 (8.39M elems, 4/thread), Wt transpose
// (first 1.05M threads), rowsum zeroing (first 16384 threads).
__global__ __launch_bounds__(256) void cvt_all_k(
    const float* __restrict__ X, uint16_t* __restrict__ Xb,
    const float* __restrict__ Wq, const float* __restrict__ Wk,
    const float* __restrict__ Wv, const float* __restrict__ Wo,
    uint16_t* __restrict__ Wt, float* __restrict__ rsum) {
  const int i = blockIdx.x * 256 + threadIdx.x;   // 0..2097151
  const float4 f = ((const float4*)X)[i];
  uint32_t lo = (uint32_t)f2bf(f.x) | ((uint32_t)f2bf(f.y) << 16);
  uint32_t hi = (uint32_t)f2bf(f.z) | ((uint32_t)f2bf(f.w) << 16);
  ((uint2*)Xb)[i] = make_uint2(lo, hi);
  if (i < 16384) rsum[i] = 0.f;
  if (i < 2048 * 512) {   // Wt[n][k] = W[k][n&511]
    const int n = i >> 9, kk = i & 511;
    const int which = n >> 9, c = n & 511;
    const float* W =
        (which == 0) ? Wq : (which == 1) ? Wk : (which == 2) ? Wv : Wo;
    Wt[i] = f2bf(W[kk * 512 + c]);
  }
}

extern "C" void kernel_launch(void* const* d_in, const int* in_sizes, int n_in,
                              void* d_out, int out_size, void* d_ws,
                              size_t ws_size, hipStream_t stream) {
  const float* X     = (const float*)d_in[0];
  const float* Wq    = (const float*)d_in[1];
  const float* bq    = (const float*)d_in[2];
  const float* Wk    = (const float*)d_in[3];
  const float* bk    = (const float*)d_in[4];
  const float* Wv    = (const float*)d_in[5];
  const float* bv    = (const float*)d_in[6];
  const float* Wo    = (const float*)d_in[7];
  const float* bo    = (const float*)d_in[8];
  const float* gamma = (const float*)d_in[9];
  const float* beta  = (const float*)d_in[10];
  float* out = (float*)d_out;

  char* ws = (char*)d_ws;   // ~114.1 MB used (overlaid layout, see header)
  uint16_t* S    = (uint16_t*)(ws);                 // [0, 64M)
  uint16_t* Xb   = (uint16_t*)(ws);                 // [0, 16M) overlay on S
  uint16_t* Wt   = (uint16_t*)(ws + 67108864);      // [64M, 66M)
  uint16_t* q    = (uint16_t*)(ws + 69206016);      // [66M, 82M), later ctx
  uint16_t* kb   = (uint16_t*)(ws + 85983232);      // [82M, 98M)
  uint16_t* vT   = (uint16_t*)(ws + 102760448);     // [98M, 114M) [8][512][2048]
  float*    rsum = (float*)(ws + 119537664);        // [114M, +64K) fp32[16384]
  uint16_t* ctx  = q;                               // overlay: q dead after scores

  cvt_all_k<<<dim3(8192), dim3(256), 0, stream>>>(X, Xb, Wq, Wk, Wv, Wo, Wt,
                                                  rsum);
  // QKV: M=16384, N=1536, K=512, tile 128x128 (1536 blocks)
  gemm_k<0, 128, 128><<<dim3(12, 128, 1), dim3(256), 0, stream>>>(
      Xb, Wt, (void*)q, kb, vT, nullptr, 512, 512, 512, bq, bk, bv, 1.f);
  // scores: per batch M=N=2048, K=512; tile 128x128 (2048 blocks)
  gemm_k<1, 128, 128><<<dim3(16, 16, 8), dim3(256), 0, stream>>>(
      q, kb, (void*)S, nullptr, nullptr, rsum, 512, 512, 512, nullptr, nullptr,
      nullptr, 0.044194173824159216f);
  // ctx = (E @ V)/rowsum: per batch M=2048, N=512, K=2048, tile 64x128
  gemm_k<2, 64, 128><<<dim3(4, 32, 8), dim3(256), 0, stream>>>(
      S, vT, (void*)ctx, nullptr, nullptr, rsum, 2048, 2048, 2048, nullptr,
      nullptr, nullptr, 1.f);
  // fused out-proj + bo + X residual + LayerNorm: M=16384, N=512, K=512,
  // tile 64x512 (256 blocks, each owns full rows)
  gemmf_k<64, 512, 1, 8><<<dim3(1, 256, 1), dim3(512), 0, stream>>>(
      ctx, Wt + 1536 * 512, (void*)out, 512, 512, 512, bo, gamma, beta, X);
}